// Round 6
// baseline (510.718 us; speedup 1.0000x reference)
//
#include <hip/hip_runtime.h>
#include <hip/hip_bf16.h>

typedef unsigned short u16;
typedef __attribute__((ext_vector_type(8))) short bf16x8;
typedef __attribute__((ext_vector_type(4))) float f32x4;

#define BK 32
#define TILE_U16 (128 * BK)

__device__ __forceinline__ u16 f2bf(float f) {
  union { float f; unsigned u; } a; a.f = f;
  unsigned r = a.u + 0x7fffu + ((a.u >> 16) & 1u);  // RNE
  return (u16)(r >> 16);
}

// Async-stage a [128 rows][32 u16] tile into LDS with a bank swizzle:
// physical 16B chunk (row, p) holds logical k-chunk (p - (row>>1)) & 3.
// 512 threads: one 16B global_load_lds each.
__device__ __forceinline__ void stage_async(const u16* __restrict__ g, int ldg,
                                            u16* __restrict__ s, int tid) {
  int lane = tid & 63, wave = tid >> 6;
  int chunk = wave * 64 + lane;
  int row = chunk >> 2;
  int kc = (chunk - (row >> 1)) & 3;
  __builtin_amdgcn_global_load_lds(
      (const __attribute__((address_space(1))) unsigned int*)(g + (long)row * ldg + kc * 8),
      (__attribute__((address_space(3))) unsigned int*)(s + wave * 512),
      16, 0, 0);
}

// Generic NCH-chunk stager (NCH multiple of 512), same swizzle.
template <int NCH>
__device__ __forceinline__ void stage_rows(const u16* __restrict__ g, int ldg,
                                           u16* __restrict__ s, int tid) {
#pragma unroll
  for (int c0 = 0; c0 < NCH; c0 += 512) {
    int c = c0 + tid;
    int row = c >> 2;
    int kc = (c - (row >> 1)) & 3;
    __builtin_amdgcn_global_load_lds(
        (const __attribute__((address_space(1))) unsigned int*)(g + (long)row * ldg + kc * 8),
        (__attribute__((address_space(3))) unsigned int*)(s + (c0 + (tid & ~63)) * 8),
        16, 0, 0);
  }
}

// ---------------- fused flash attention: scores+softmax+attnV ----------------
// One block = (batch, 128-query tile). 512 threads (8 waves, 4x2 wave grid).
// S-phase: S = Q K^T (K=512, 16 chunks). PV: O += P V^T (per 128-key tile).
__global__ __launch_bounds__(512, 2) void flash_kernel(
    const u16* __restrict__ qT, const u16* __restrict__ kT,
    const u16* __restrict__ vN, u16* __restrict__ aoT) {
  __shared__ __align__(16) u16 stg[2][8192];   // 2 x 16KB: S: Q@0,K@4096 | PV: V half-chunk
  __shared__ __align__(16) u16 Plds[16384];    // 128x128 bf16 P, 16B-chunk swizzled
  float* fov = (float*)&stg[1][0];  // overlay (dead staging): maxp[256] sump[256] mnew[128] alpha[128]

  const int tid = threadIdx.x;
  const int lane = tid & 63, wave = tid >> 6;
  const int lrow = lane & 15, quad = lane >> 4;
  const int wg = wave >> 1, wh = wave & 1;   // 4x2 wave grid (both phases)
  const int b = blockIdx.y, qt = blockIdx.x;
  const long SB = 512L * 1024;
  const u16* qb = qT + (long)b * SB + (long)(qt * 128) * 512;
  const u16* kb = kT + (long)b * SB;
  const u16* vb = vN + (long)b * SB;
  const float scale = 0.044194173824159216f;  // 512^-0.5

  int aq[2], bkf[4], av[4], qc[4];
#pragma unroll
  for (int mt = 0; mt < 2; ++mt) { int r = wg * 32 + mt * 16 + lrow; aq[mt] = r * 32 + ((quad + (r >> 1)) & 3) * 8; }
#pragma unroll
  for (int nt = 0; nt < 4; ++nt) { int r = wh * 64 + nt * 16 + lrow; bkf[nt] = 4096 + r * 32 + ((quad + (r >> 1)) & 3) * 8; }
#pragma unroll
  for (int mt = 0; mt < 4; ++mt) { int r = wg * 64 + mt * 16 + lrow; av[mt] = r * 32 + ((quad + (r >> 1)) & 3) * 8; }
#pragma unroll
  for (int nt = 0; nt < 4; ++nt) qc[nt] = wh * 64 + nt * 16 + lrow;

  float m_r = -INFINITY, l_r = 0.f;  // per-row state, owned by tid<128 (row = tid)
  f32x4 acc_o[2][4][4];              // [ch-half][mt=ch][nt=q]
#pragma unroll
  for (int h = 0; h < 2; ++h)
#pragma unroll
    for (int mt = 0; mt < 4; ++mt)
#pragma unroll
      for (int nt = 0; nt < 4; ++nt) acc_o[h][mt][nt] = (f32x4){0.f, 0.f, 0.f, 0.f};

  // prologue: stage tile-0 S chunk 0
  stage_rows<512>(qb, 512, stg[0], tid);
  stage_rows<512>(kb, 512, stg[0] + 4096, tid);

  for (int t = 0; t < 8; ++t) {
    const u16* kbt = kb + (long)t * (128 * 512);
    f32x4 acc_s[2][4];
#pragma unroll
    for (int mt = 0; mt < 2; ++mt)
#pragma unroll
      for (int nt = 0; nt < 4; ++nt) acc_s[mt][nt] = (f32x4){0.f, 0.f, 0.f, 0.f};

    // ---- S = Q K^T over 16 K-chunks ----
    for (int c = 0; c < 16; ++c) {
      __syncthreads();                       // drains stage of chunk c
      int buf = c & 1;
      if (c < 15) {
        stage_rows<512>(qb + (c + 1) * 32, 512, stg[buf ^ 1], tid);
        stage_rows<512>(kbt + (c + 1) * 32, 512, stg[buf ^ 1] + 4096, tid);
      }
      bf16x8 af[2], bf[4];
#pragma unroll
      for (int mt = 0; mt < 2; ++mt) af[mt] = *(const bf16x8*)&stg[buf][aq[mt]];
#pragma unroll
      for (int nt = 0; nt < 4; ++nt) bf[nt] = *(const bf16x8*)&stg[buf][bkf[nt]];
#pragma unroll
      for (int mt = 0; mt < 2; ++mt)
#pragma unroll
        for (int nt = 0; nt < 4; ++nt)
          acc_s[mt][nt] = __builtin_amdgcn_mfma_f32_16x16x32_bf16(af[mt], bf[nt], acc_s[mt][nt], 0, 0, 0);
    }
    __syncthreads();  // (a0) all S reads done; stg free

    // scale + per-row max partials
#pragma unroll
    for (int mt = 0; mt < 2; ++mt)
#pragma unroll
      for (int nt = 0; nt < 4; ++nt) acc_s[mt][nt] *= scale;
    float rmax[2][4];
#pragma unroll
    for (int mt = 0; mt < 2; ++mt)
#pragma unroll
      for (int r = 0; r < 4; ++r) {
        float m0 = fmaxf(acc_s[mt][0][r], acc_s[mt][1][r]);
        float m1 = fmaxf(acc_s[mt][2][r], acc_s[mt][3][r]);
        rmax[mt][r] = fmaxf(m0, m1);
      }
#pragma unroll
    for (int off = 1; off < 16; off <<= 1)
#pragma unroll
      for (int mt = 0; mt < 2; ++mt)
#pragma unroll
        for (int r = 0; r < 4; ++r) rmax[mt][r] = fmaxf(rmax[mt][r], __shfl_xor(rmax[mt][r], off));
    if (lrow == 0) {
#pragma unroll
      for (int mt = 0; mt < 2; ++mt)
#pragma unroll
        for (int r = 0; r < 4; ++r)
          fov[(wg * 32 + mt * 16 + quad * 4 + r) * 2 + wh] = rmax[mt][r];
    }
    // prefetch first V half-chunk of this key tile into stg[0]
    stage_rows<1024>(vb + t * 128, 1024, stg[0], tid);
    __syncthreads();  // (a)

    float alpha_r = 0.f;
    if (tid < 128) {
      float mt_ = fmaxf(fov[tid * 2], fov[tid * 2 + 1]);
      float mnew = fmaxf(m_r, mt_);
      alpha_r = __expf(m_r - mnew);
      m_r = mnew;
      fov[512 + tid] = mnew;
      fov[640 + tid] = alpha_r;
    }
    __syncthreads();  // (b)

    // P = exp(S - m_new), bf16 -> Plds; row-sum partials
    float psum[2][4];
#pragma unroll
    for (int mt = 0; mt < 2; ++mt)
#pragma unroll
      for (int r = 0; r < 4; ++r) psum[mt][r] = 0.f;
#pragma unroll
    for (int mt = 0; mt < 2; ++mt)
#pragma unroll
      for (int r = 0; r < 4; ++r) {
        int row = wg * 32 + mt * 16 + quad * 4 + r;
        float mn = fov[512 + row];
#pragma unroll
        for (int nt = 0; nt < 4; ++nt) {
          float p = __expf(acc_s[mt][nt][r] - mn);
          psum[mt][r] += p;
          int key = wh * 64 + nt * 16 + lrow;
          Plds[row * 128 + (((key >> 3) + row) & 15) * 8 + (key & 7)] = f2bf(p);
        }
      }
#pragma unroll
    for (int off = 1; off < 16; off <<= 1)
#pragma unroll
      for (int mt = 0; mt < 2; ++mt)
#pragma unroll
        for (int r = 0; r < 4; ++r) psum[mt][r] += __shfl_xor(psum[mt][r], off);
    if (lrow == 0) {
#pragma unroll
      for (int mt = 0; mt < 2; ++mt)
#pragma unroll
        for (int r = 0; r < 4; ++r)
          fov[256 + (wg * 32 + mt * 16 + quad * 4 + r) * 2 + wh] = psum[mt][r];
    }
    __syncthreads();  // (c) Plds ready, sum partials ready, V(0) drained

    if (tid < 128) l_r = alpha_r * l_r + fov[256 + tid * 2] + fov[256 + tid * 2 + 1];
    float a4[4];
#pragma unroll
    for (int nt = 0; nt < 4; ++nt) a4[nt] = fov[640 + qc[nt]];
#pragma unroll
    for (int h = 0; h < 2; ++h)
#pragma unroll
      for (int mt = 0; mt < 4; ++mt)
#pragma unroll
        for (int nt = 0; nt < 4; ++nt) acc_o[h][mt][nt] *= a4[nt];

    // ---- PV: 2 ch-halves x 4 key-chunks ----
    for (int j = 0; j < 8; ++j) {
      __syncthreads();  // guards prefetch target (j=0: rescale/alpha reads done)
      if (j < 7) {
        int jn = j + 1;
        stage_rows<1024>(vb + (long)((jn >> 2) * 256) * 1024 + t * 128 + (jn & 3) * 32,
                         1024, stg[jn & 1], tid);
      } else if (t < 7) {
        stage_rows<512>(qb, 512, stg[0], tid);                     // next tile S chunk 0
        stage_rows<512>(kbt + 128 * 512, 512, stg[0] + 4096, tid);
      }
      int half = j >> 2, cc = j & 3;
      bf16x8 afv[4], bfp[4];
#pragma unroll
      for (int mt = 0; mt < 4; ++mt) afv[mt] = *(const bf16x8*)&stg[j & 1][av[mt]];
#pragma unroll
      for (int nt = 0; nt < 4; ++nt)
        bfp[nt] = *(const bf16x8*)&Plds[qc[nt] * 128 + (((cc * 4 + quad) + qc[nt]) & 15) * 8];
#pragma unroll
      for (int mt = 0; mt < 4; ++mt)
#pragma unroll
        for (int nt = 0; nt < 4; ++nt)
          acc_o[half][mt][nt] = __builtin_amdgcn_mfma_f32_16x16x32_bf16(afv[mt], bfp[nt], acc_o[half][mt][nt], 0, 0, 0);
    }
  }

  // epilogue: O /= l, write aoT[q][ch] bf16 (uint2 of 4 consecutive ch)
  __syncthreads();
  if (tid < 128) fov[tid] = 1.f / l_r;
  __syncthreads();
  float li[4];
#pragma unroll
  for (int nt = 0; nt < 4; ++nt) li[nt] = fov[qc[nt]];
#pragma unroll
  for (int h = 0; h < 2; ++h)
#pragma unroll
    for (int mt = 0; mt < 4; ++mt)
#pragma unroll
      for (int nt = 0; nt < 4; ++nt) {
        f32x4 o = acc_o[h][mt][nt];
        int ch = h * 256 + wg * 64 + mt * 16 + quad * 4;
        long idx = (long)b * SB + (long)(qt * 128 + qc[nt]) * 512 + ch;
        uint2 st;
        st.x = (unsigned)f2bf(o[0] * li[nt]) | ((unsigned)f2bf(o[1] * li[nt]) << 16);
        st.y = (unsigned)f2bf(o[2] * li[nt]) | ((unsigned)f2bf(o[3] * li[nt]) << 16);
        *(uint2*)&aoT[idx] = st;
      }
}

// ---------------- batched GEMM (QKV merged / proj), unchanged core ----------------
__device__ __forceinline__ void gemm_core(
    const u16* __restrict__ Ab, const u16* __restrict__ Bb,
    int lda, int ldb, int K, int tid,
    u16* __restrict__ As, u16* __restrict__ Bs, f32x4 (&acc)[2][4]) {
  int lane = tid & 63, wave = tid >> 6;
  int wr = wave >> 1, wc = wave & 1;
  int lrow = lane & 15, quad = lane >> 4;
  int aoff[2], boff[4];
#pragma unroll
  for (int mt = 0; mt < 2; ++mt) {
    int row = wr * 32 + mt * 16 + lrow;
    aoff[mt] = row * BK + ((quad + (row >> 1)) & 3) * 8;
  }
#pragma unroll
  for (int nt = 0; nt < 4; ++nt) {
    int row = wc * 64 + nt * 16 + lrow;
    boff[nt] = row * BK + ((quad + (row >> 1)) & 3) * 8;
  }
#pragma unroll
  for (int i = 0; i < 2; ++i)
#pragma unroll
    for (int j = 0; j < 4; ++j) acc[i][j] = (f32x4){0.f, 0.f, 0.f, 0.f};

  stage_async(Ab, lda, As, tid);
  stage_async(Bb, ldb, Bs, tid);
  int cur = 0;
  for (int k0 = 0; k0 < K; k0 += BK) {
    __syncthreads();
    if (k0 + BK < K) {
      stage_async(Ab + k0 + BK, lda, As + (cur ^ 1) * TILE_U16, tid);
      stage_async(Bb + k0 + BK, ldb, Bs + (cur ^ 1) * TILE_U16, tid);
    }
    const u16* Ac = As + cur * TILE_U16;
    const u16* Bc = Bs + cur * TILE_U16;
    bf16x8 af[2], bfr[4];
#pragma unroll
    for (int mt = 0; mt < 2; ++mt) af[mt] = *(const bf16x8*)&Ac[aoff[mt]];
#pragma unroll
    for (int nt = 0; nt < 4; ++nt) bfr[nt] = *(const bf16x8*)&Bc[boff[nt]];
#pragma unroll
    for (int mt = 0; mt < 2; ++mt)
#pragma unroll
      for (int nt = 0; nt < 4; ++nt)
        acc[mt][nt] = __builtin_amdgcn_mfma_f32_16x16x32_bf16(af[mt], bfr[nt], acc[mt][nt], 0, 0, 0);
    cur ^= 1;
  }
}

__device__ __forceinline__ void epi_trans_bf16(
    f32x4 (&acc)[2][4], u16* __restrict__ C, long cbase, int m0, int n0, int ldc,
    const float* __restrict__ bias, int tid) {
  int lane = tid & 63, wave = tid >> 6;
  int wr = wave >> 1, wc = wave & 1;
  int lrow = lane & 15, quad = lane >> 4;
#pragma unroll
  for (int mt = 0; mt < 2; ++mt) {
    int rowbase = m0 + wr * 32 + mt * 16 + quad * 4;
    float4 b4 = bias ? *(const float4*)&bias[rowbase] : make_float4(0.f, 0.f, 0.f, 0.f);
#pragma unroll
    for (int nt = 0; nt < 4; ++nt) {
      int col = n0 + wc * 64 + nt * 16 + lrow;
      f32x4 a = acc[mt][nt];
      uint2 o;
      o.x = (unsigned)f2bf(a[0] + b4.x) | ((unsigned)f2bf(a[1] + b4.y) << 16);
      o.y = (unsigned)f2bf(a[2] + b4.z) | ((unsigned)f2bf(a[3] + b4.w) << 16);
      *(uint2*)(C + cbase + (long)col * ldc + rowbase) = o;
    }
  }
}

// MODE: 2 = natural fp32 + bias + residual (proj), 3 = merged QKV.
template <int MODE>
__global__ __launch_bounds__(512, 4) void gemm_kernel(
    const u16* __restrict__ Ag, const u16* __restrict__ Bg,
    void* __restrict__ C0, void* __restrict__ C1, void* __restrict__ C2,
    const float* __restrict__ bias0, const float* __restrict__ bias1,
    const float* __restrict__ bias2, const float* __restrict__ resid,
    int lda, int ldb, int ldc,
    long strideA, long strideB, long strideC, int K) {
  __shared__ __align__(16) u16 As[2 * TILE_U16];
  __shared__ __align__(16) u16 Bs[2 * TILE_U16];
  int tid = threadIdx.x;
  int b = blockIdx.z;
  int m0 = blockIdx.y * 128, n0 = blockIdx.x * 128;
  const u16* Ab = Ag + (long)b * strideA + (long)m0 * lda;
  const u16* Bb = Bg + (long)b * strideB + (long)n0 * ldb;
  f32x4 acc[2][4];
  gemm_core(Ab, Bb, lda, ldb, K, tid, As, Bs, acc);

  int lane = tid & 63, wave = tid >> 6;
  int wr = wave >> 1, wc = wave & 1;
  int lrow = lane & 15, quad = lane >> 4;
  long cbase = (long)b * strideC;

  if (MODE == 2) {
#pragma unroll
    for (int mt = 0; mt < 2; ++mt)
#pragma unroll
      for (int r = 0; r < 4; ++r) {
        int row = m0 + wr * 32 + mt * 16 + quad * 4 + r;
        float bv = bias0[row];
#pragma unroll
        for (int nt = 0; nt < 4; ++nt) {
          int col = n0 + wc * 64 + nt * 16 + lrow;
          long idx = cbase + (long)row * ldc + col;
          ((float*)C0)[idx] = acc[mt][nt][r] + bv + resid[idx];
        }
      }
  } else {  // merged QKV: A-row segments of 512: q(trans), k(trans), v(natural)
    int seg = m0 >> 9;
    int ml = m0 & 511;
    if (seg == 0) {
      epi_trans_bf16(acc, (u16*)C0, cbase, ml, n0, 512, bias0, tid);
    } else if (seg == 1) {
      epi_trans_bf16(acc, (u16*)C1, cbase, ml, n0, 512, bias1, tid);
    } else {
#pragma unroll
      for (int mt = 0; mt < 2; ++mt)
#pragma unroll
        for (int r = 0; r < 4; ++r) {
          int row = ml + wr * 32 + mt * 16 + quad * 4 + r;
          float bv = bias2[row];
#pragma unroll
          for (int nt = 0; nt < 4; ++nt) {
            int col = n0 + wc * 64 + nt * 16 + lrow;
            ((u16*)C2)[cbase + (long)row * 1024 + col] = f2bf(acc[mt][nt][r] + bv);
          }
        }
    }
  }
}

// One block per (group, batch): 32 channels x 1024 tokens. Writes hn TOKEN-MAJOR.
__global__ __launch_bounds__(256) void groupnorm_kernel(
    const float* __restrict__ x, const float* __restrict__ gamma,
    const float* __restrict__ beta, u16* __restrict__ hnT) {
  int g = blockIdx.x, b = blockIdx.y;
  const float* xb = x + ((long)b * 512 + g * 32) * 1024;
  int tid = threadIdx.x;
  float s = 0.f, sq = 0.f;
  float4 vals[32];
#pragma unroll
  for (int j = 0; j < 32; ++j) {
    float4 v = *(const float4*)(xb + (long)j * 1024 + tid * 4);
    vals[j] = v;
    s += v.x + v.y + v.z + v.w;
    sq += v.x * v.x + v.y * v.y + v.z * v.z + v.w * v.w;
  }
#pragma unroll
  for (int off = 1; off < 64; off <<= 1) {
    s += __shfl_xor(s, off);
    sq += __shfl_xor(sq, off);
  }
  __shared__ float ls[4], lq[4];
  if ((tid & 63) == 0) { ls[tid >> 6] = s; lq[tid >> 6] = sq; }
  __syncthreads();
  float ts = ls[0] + ls[1] + ls[2] + ls[3];
  float tq = lq[0] + lq[1] + lq[2] + lq[3];
  float mean = ts * (1.f / 32768.f);
  float var = tq * (1.f / 32768.f) - mean * mean;
  float rstd = rsqrtf(var + 1e-6f);
  u16* hb = hnT + (long)b * (1024 * 512) + g * 32;
#pragma unroll
  for (int t = 0; t < 4; ++t) {
    u16 row[32];
#pragma unroll
    for (int j = 0; j < 32; ++j) {
      float xv = ((const float*)&vals[j])[t];
      row[j] = f2bf((xv - mean) * rstd * gamma[g * 32 + j] + beta[g * 32 + j]);
    }
    uint4* dst = (uint4*)(hb + (long)(tid * 4 + t) * 512);
    const uint4* src = (const uint4*)row;
    dst[0] = src[0]; dst[1] = src[1]; dst[2] = src[2]; dst[3] = src[3];
  }
}

// Convert the 4 weight matrices (512x512 fp32) to bf16, packed contiguously.
__global__ __launch_bounds__(256) void convertw_kernel(
    const float* __restrict__ w0, const float* __restrict__ w1,
    const float* __restrict__ w2, const float* __restrict__ w3,
    u16* __restrict__ out) {
  int wsel = blockIdx.x >> 8;
  const float* src = wsel == 0 ? w0 : wsel == 1 ? w1 : wsel == 2 ? w2 : w3;
  int idx = ((blockIdx.x & 255) * 256 + threadIdx.x) * 4;
  float4 v = *(const float4*)(src + idx);
  uint2 o;
  o.x = (unsigned)f2bf(v.x) | ((unsigned)f2bf(v.y) << 16);
  o.y = (unsigned)f2bf(v.z) | ((unsigned)f2bf(v.w) << 16);
  *(uint2*)(out + (long)wsel * 262144 + idx) = o;
}

extern "C" void kernel_launch(void* const* d_in, const int* in_sizes, int n_in,
                              void* d_out, int out_size, void* d_ws, size_t ws_size,
                              hipStream_t stream) {
  const float* x     = (const float*)d_in[0];
  const float* gamma = (const float*)d_in[1];
  const float* beta  = (const float*)d_in[2];
  const float* wq    = (const float*)d_in[3];
  const float* bq    = (const float*)d_in[4];
  const float* wk    = (const float*)d_in[5];
  const float* bk    = (const float*)d_in[6];
  const float* wv    = (const float*)d_in[7];
  const float* bv    = (const float*)d_in[8];
  const float* wp    = (const float*)d_in[9];
  const float* bp    = (const float*)d_in[10];
  float* out = (float*)d_out;
  char* ws = (char*)d_ws;

  // Workspace (130 MB) — no score buffer (flash-fused)
  u16* wbf = (u16*)ws;                      //   2 MB: wq|wk|wv|wp bf16 [o][c], packed
  u16* hnT = (u16*)(ws + (2L << 20));       //  32 MB: [b][n][c]  (reused for aoT)
  u16* qT  = (u16*)(ws + (34L << 20));      //  32 MB: [b][n][c]
  u16* kT  = (u16*)(ws + (66L << 20));      //  32 MB: [b][m][c]
  u16* v   = (u16*)(ws + (98L << 20));      //  32 MB: [b][c][m]
  u16* aoT = hnT;

  const long SB = 512L * 1024;

  convertw_kernel<<<1024, 256, 0, stream>>>(wq, wk, wv, wp, wbf);
  groupnorm_kernel<<<dim3(16, 32), 256, 0, stream>>>(x, gamma, beta, hnT);

  // Merged QKV: A = [wq;wk;wv] (1536x512), B = hnT [n][c]. q,k -> token-major; v natural.
  gemm_kernel<3><<<dim3(8, 12, 32), 512, 0, stream>>>(
      wbf, hnT, qT, kT, v, bq, bk, bv, nullptr,
      512, 512, 0, 0, SB, SB, 512);

  // Fused scores+softmax+attnV -> aoT token-major
  flash_kernel<<<dim3(8, 32), 512, 0, stream>>>(qT, kT, v, aoT);

  // Proj + bias + residual -> fp32 d_out (natural [c][n]).
  gemm_kernel<2><<<dim3(8, 4, 32), 512, 0, stream>>>(
      wbf + 3 * 262144, aoT, out, nullptr, nullptr, bp, nullptr, nullptr, x,
      512, 512, 1024, 0, SB, SB, 512);
}